// Round 25
// baseline (376.283 us; speedup 1.0000x reference)
//
#include <hip/hip_runtime.h>
#include <hip/hip_bf16.h>

typedef unsigned short u16;
typedef unsigned int u32;
typedef __attribute__((ext_vector_type(8))) short short8;   // 8 bf16 — MFMA A/B frag
typedef __attribute__((ext_vector_type(4))) float f32x4;    // MFMA C/D frag

__device__ __forceinline__ u16 bf16_rne(float x) {
  __hip_bfloat16 h = __float2bfloat16(x);   // RNE
  return __builtin_bit_cast(u16, h);
}

// ---------------------------------------------------------------------------
// Kernel 1: per-token per-128-group fp8 quantize + dequantize A -> bf16 [M,K].
// A is f32 row-major [M,K] (numpy-materialized bf16 values).
// a_deq = bf16(fp8_rne(clip(a/scale, ±448)) * scale), scale = max(amax,1e-4)/448.
// Verified: produces refTrue[0,0]-matching output at (0,0) [r18/r19].
// ---------------------------------------------------------------------------
__global__ __launch_bounds__(256) void quant_dequant_a(
    const float* __restrict__ A, u16* __restrict__ AD, int K) {
  const int b = blockIdx.x;
  const int row = b >> 1;                  // 2 blocks per row (K=4096)
  const int t = threadIdx.x;
  const size_t base = (size_t)row * K + (size_t)(b & 1) * 2048 + (size_t)t * 8;

  float4 v0 = *(const float4*)(A + base);
  float4 v1 = *(const float4*)(A + base + 4);
  float f[8] = {v0.x, v0.y, v0.z, v0.w, v1.x, v1.y, v1.z, v1.w};

  float am = 0.f;
#pragma unroll
  for (int i = 0; i < 8; ++i) am = fmaxf(am, fabsf(f[i]));
  // group of 128 = 16 consecutive lanes
  am = fmaxf(am, __shfl_xor(am, 1));
  am = fmaxf(am, __shfl_xor(am, 2));
  am = fmaxf(am, __shfl_xor(am, 4));
  am = fmaxf(am, __shfl_xor(am, 8));
  const float scale = fmaxf(am, 1e-4f) / 448.0f;   // IEEE div, matches reference

  u16 o[8];
#pragma unroll
  for (int i = 0; i < 8; ++i) {
    float qv = fminf(fmaxf(f[i] / scale, -448.f), 448.f);
    int pk = __builtin_amdgcn_cvt_pk_fp8_f32(qv, qv, 0, false);  // OCP e4m3fn RNE
    float dv = __builtin_amdgcn_cvt_f32_fp8(pk, 0) * scale;
    o[i] = bf16_rne(dv);
  }
  *(uint4*)(AD + base) = *(const uint4*)o;
}

// ---------------------------------------------------------------------------
// Kernel 2: bf16 MFMA GEMM over FULL M x N (r10 structure, oracle-verified):
// O[m][n] = sum_k AD[m][k] * bf16(W[n][k]*ws[n/128][k/128]).
// *** d_out is FLOAT32[M*N] *** (numpy-materialized bf16 output — r24 proof).
// Store out_u32[m*N+n] = bf16bits(O) << 16  (= f32 upcast of bf16 value,
// exactly the reference's bf16-round-then-upcast form).
// ---------------------------------------------------------------------------
#define LSTR 72   // LDS row stride in bf16 units (64 data + 8 pad)

__global__ __launch_bounds__(256, 2) void gemm_bf16_fused(
    const u16* __restrict__ AD, const float* __restrict__ Wf,
    const float* __restrict__ WS, u32* __restrict__ C32,
    int M, int N, int K) {
  __shared__ __align__(16) u16 As[128 * LSTR];
  __shared__ __align__(16) u16 Bs[128 * LSTR];

  const int NBN = N >> 7;                      // 32
  const int bm = blockIdx.x / NBN;
  const int bn = blockIdx.x % NBN;

  const int tid = threadIdx.x, lane = tid & 63;
  const int wid = tid >> 6;
  const int wm = wid >> 1, wn = wid & 1;       // 2x2 wave grid, 64x64 per wave

  f32x4 acc[4][4];
#pragma unroll
  for (int mi = 0; mi < 4; ++mi)
#pragma unroll
    for (int ni = 0; ni < 4; ++ni)
      acc[mi][ni] = (f32x4){0.f, 0.f, 0.f, 0.f};

  const int KT = K >> 6;                       // 64 K-tiles of 64 bf16
  for (int g = 0; g < KT; ++g) {
    const float wsv = WS[bn * (K >> 7) + (g >> 1)];  // ws[n/128][k/128]
    __syncthreads();                           // protect prev-iter LDS reads
#pragma unroll
    for (int it = 0; it < 4; ++it) {
      const int ci = it * 256 + tid;
      const int r = ci >> 3, c = ci & 7;       // row 0..127, chunk 0..7 (8 elems)
      uint4 av = *(const uint4*)(AD + (size_t)(bm * 128 + r) * K + g * 64 + c * 8);
      *(uint4*)(As + r * LSTR + c * 8) = av;
      const float* bsrc = Wf + (size_t)(bn * 128 + r) * K + g * 64 + c * 8;
      float4 b0 = ((const float4*)bsrc)[0];
      float4 b1 = ((const float4*)bsrc)[1];
      u16 o[8];
      o[0] = bf16_rne(b0.x * wsv); o[1] = bf16_rne(b0.y * wsv);
      o[2] = bf16_rne(b0.z * wsv); o[3] = bf16_rne(b0.w * wsv);
      o[4] = bf16_rne(b1.x * wsv); o[5] = bf16_rne(b1.y * wsv);
      o[6] = bf16_rne(b1.z * wsv); o[7] = bf16_rne(b1.w * wsv);
      *(uint4*)(Bs + r * LSTR + c * 8) = *(const uint4*)o;
    }
    __syncthreads();

#pragma unroll
    for (int kk = 0; kk < 2; ++kk) {
      const int ko = kk * 32 + ((lane >> 4) << 3);   // 8-elem frag along K
      short8 af[4], bfr[4];
#pragma unroll
      for (int mi = 0; mi < 4; ++mi) {
        const int rw = wm * 64 + mi * 16 + (lane & 15);
        af[mi] = *(const short8*)(As + rw * LSTR + ko);
      }
#pragma unroll
      for (int ni = 0; ni < 4; ++ni) {
        const int rw = wn * 64 + ni * 16 + (lane & 15);
        bfr[ni] = *(const short8*)(Bs + rw * LSTR + ko);
      }
#pragma unroll
      for (int mi = 0; mi < 4; ++mi)
#pragma unroll
        for (int ni = 0; ni < 4; ++ni)
          acc[mi][ni] = __builtin_amdgcn_mfma_f32_16x16x32_bf16(af[mi], bfr[ni], acc[mi][ni], 0, 0, 0);
    }
  }

  // epilogue: m89 C/D mapping; f32 store = bf16 bits in high half, low half 0
  const int col = bn * 128 + wn * 64 + (lane & 15);
#pragma unroll
  for (int mi = 0; mi < 4; ++mi) {
#pragma unroll
    for (int j = 0; j < 4; ++j) {
      const size_t row = (size_t)(bm * 128 + wm * 64 + mi * 16 + ((lane >> 4) << 2) + j);
#pragma unroll
      for (int ni = 0; ni < 4; ++ni) {
        C32[row * N + col + ni * 16] = ((u32)bf16_rne(acc[mi][ni][j])) << 16;
      }
    }
  }
}

// ---------------------------------------------------------------------------
extern "C" void kernel_launch(void* const* d_in, const int* in_sizes, int n_in,
                              void* d_out, int out_size, void* d_ws, size_t ws_size,
                              hipStream_t stream) {
  const float* A = (const float*)d_in[0];    // f32 row-major [M,K]
  const float* W = (const float*)d_in[1];    // f32 row-major [N,K]
  const float* WS = (const float*)d_in[2];   // f32 [N/128,K/128]
  const int K = 4096, N = 4096;
  const int M = in_sizes[0] / K;             // 8192

  u16* AD = (u16*)d_ws;                      // 64 MiB — only workspace use

  quant_dequant_a<<<M * 2, 256, 0, stream>>>(A, AD, K);
  gemm_bf16_fused<<<(M / 128) * (N / 128), 256, 0, stream>>>(
      AD, W, WS, (u32*)d_out, M, N, K);
}

// Round 26
// 301.372 us; speedup vs baseline: 1.2486x; 1.2486x over previous
//
#include <hip/hip_runtime.h>
#include <hip/hip_bf16.h>

typedef unsigned short u16;
typedef unsigned int u32;
typedef __attribute__((ext_vector_type(8))) short short8;   // 8 bf16 — MFMA A/B frag
typedef __attribute__((ext_vector_type(4))) float f32x4;    // MFMA C/D frag

__device__ __forceinline__ u16 bf16_rne(float x) {
  __hip_bfloat16 h = __float2bfloat16(x);   // RNE
  return __builtin_bit_cast(u16, h);
}

// ---------------------------------------------------------------------------
// Kernel 1: per-token per-128-group fp8 quantize + dequantize A -> bf16.
// A f32 row-major; processes 4096 rows per launch (host offsets pointer).
// ---------------------------------------------------------------------------
__global__ __launch_bounds__(256) void quant_dequant_a(
    const float* __restrict__ A, u16* __restrict__ AD, int K) {
  const int b = blockIdx.x;
  const int row = b >> 1;
  const int t = threadIdx.x;
  const size_t base = (size_t)row * K + (size_t)(b & 1) * 2048 + (size_t)t * 8;

  float4 v0 = *(const float4*)(A + base);
  float4 v1 = *(const float4*)(A + base + 4);
  float f[8] = {v0.x, v0.y, v0.z, v0.w, v1.x, v1.y, v1.z, v1.w};

  float am = 0.f;
#pragma unroll
  for (int i = 0; i < 8; ++i) am = fmaxf(am, fabsf(f[i]));
  am = fmaxf(am, __shfl_xor(am, 1));
  am = fmaxf(am, __shfl_xor(am, 2));
  am = fmaxf(am, __shfl_xor(am, 4));
  am = fmaxf(am, __shfl_xor(am, 8));
  const float scale = fmaxf(am, 1e-4f) / 448.0f;

  u16 o[8];
#pragma unroll
  for (int i = 0; i < 8; ++i) {
    float qv = fminf(fmaxf(f[i] / scale, -448.f), 448.f);
    int pk = __builtin_amdgcn_cvt_pk_fp8_f32(qv, qv, 0, false);  // OCP e4m3fn RNE
    float dv = __builtin_amdgcn_cvt_f32_fp8(pk, 0) * scale;
    o[i] = bf16_rne(dv);
  }
  *(uint4*)(AD + base) = *(const uint4*)o;
}

// ---------------------------------------------------------------------------
// Kernel 2: dequantize W once: WD[n][k] = bf16(W[n][k] * ws[n/128][k/128]).
// ---------------------------------------------------------------------------
__global__ __launch_bounds__(256) void dequant_w(
    const float* __restrict__ W, const float* __restrict__ WS,
    u16* __restrict__ WD, int K, int KG) {
  const int b = blockIdx.x;
  const int n = b >> 1;
  const int t = threadIdx.x;
  const int kof = (b & 1) * 2048 + t * 8;
  const float ws = WS[(n >> 7) * KG + (kof >> 7)];
  const size_t base = (size_t)n * K + kof;
  float4 v0 = *(const float4*)(W + base);
  float4 v1 = *(const float4*)(W + base + 4);
  u16 o[8];
  o[0] = bf16_rne(v0.x * ws); o[1] = bf16_rne(v0.y * ws);
  o[2] = bf16_rne(v0.z * ws); o[3] = bf16_rne(v0.w * ws);
  o[4] = bf16_rne(v1.x * ws); o[5] = bf16_rne(v1.y * ws);
  o[6] = bf16_rne(v1.z * ws); o[7] = bf16_rne(v1.w * ws);
  *(uint4*)(WD + base) = *(const uint4*)o;
}

// ---------------------------------------------------------------------------
// Kernel 3: pipelined 256x256 bf16 GEMM (4-phase/K-tile, dbuf LDS, glds w16,
// XOR chunk swizzle, setprio, single counted drain per K-tile).
// C32[m][n] (f32-as-u32, bf16 bits << 16) = sum_k AD[m][k]*WD[n][k].
// Mh = 4096 rows per launch; grid 256 blocks x 512 threads; LDS 128 KiB.
// ---------------------------------------------------------------------------
#define GLDS16(g, l) __builtin_amdgcn_global_load_lds( \
    (const __attribute__((address_space(1))) void*)(g), \
    (__attribute__((address_space(3))) void*)(l), 16, 0, 0)

#define STAGE2(TILE, R, BUF) do { \
    GLDS16(A8 + (size_t)(arow0 + (R)*64 + srow) * rs + (size_t)(TILE)*128 + scs, \
           sA + (BUF)*32768 + (R)*8192 + tid*16); \
    GLDS16(B8 + (size_t)(brow0 + (R)*64 + srow) * rs + (size_t)(TILE)*128 + scs, \
           sB + (BUF)*32768 + (R)*8192 + tid*16); \
  } while (0)

#define READ_A(H) \
  _Pragma("unroll") for (int mi2 = 0; mi2 < 4; ++mi2) \
    _Pragma("unroll") for (int kk = 0; kk < 2; ++kk) \
      a[mi2][kk] = *(const short8*)(Ab + (rA0 + (H)*64 + mi2*16)*128 + \
                                    ((((kk<<2)|kq)^swA)<<4));

#define READ_B(NI0) \
  _Pragma("unroll") for (int ni2 = 0; ni2 < 2; ++ni2) \
    _Pragma("unroll") for (int kk = 0; kk < 2; ++kk) \
      bfr[(NI0)+ni2][kk] = *(const short8*)(Bb + (rB0 + ((NI0)+ni2)*16)*128 + \
                                            ((((kk<<2)|kq)^swB)<<4));

#define MFMA_Q(MH, NH) do { \
    __builtin_amdgcn_s_setprio(1); \
    _Pragma("unroll") for (int mi2 = 0; mi2 < 4; ++mi2) \
      _Pragma("unroll") for (int ni2 = 0; ni2 < 2; ++ni2) \
        _Pragma("unroll") for (int kk = 0; kk < 2; ++kk) \
          acc[(MH)*4+mi2][(NH)*2+ni2] = __builtin_amdgcn_mfma_f32_16x16x32_bf16( \
              a[mi2][kk], bfr[(NH)*2+ni2][kk], acc[(MH)*4+mi2][(NH)*2+ni2], 0, 0, 0); \
    __builtin_amdgcn_s_setprio(0); \
  } while (0)

__global__ __launch_bounds__(512, 2) void gemm_8p(
    const u16* __restrict__ AD, const u16* __restrict__ WD,
    u32* __restrict__ C32, int N, int K) {
  __shared__ __align__(16) uint8_t smem[131072];   // As[2][32KB] | Bs[2][32KB]
  uint8_t* sA = smem;
  uint8_t* sB = smem + 65536;

  const int NBN = N >> 8;                     // 16
  int b = blockIdx.x;
  const int per = gridDim.x >> 3;             // XCD swizzle (grid 256 % 8 == 0)
  b = (b & 7) * per + (b >> 3);
  const int bm = b / NBN, bn = b % NBN;

  const int tid = threadIdx.x, lane = tid & 63, wid = tid >> 6;
  const int wm = wid >> 2, wn = wid & 3;      // 2x4 wave grid, 128x64 per wave

  const uint8_t* A8 = (const uint8_t*)AD;
  const uint8_t* B8 = (const uint8_t*)WD;
  const size_t rs = (size_t)K * 2;

  // staging constants: round = 64 rows; thread covers (row srow, chunk sc)
  const int srow = tid >> 3;                  // 0..63
  const int sc   = tid & 7;
  const int scs  = (sc ^ (srow & 7)) << 4;    // inverse-swizzled global chunk
  const int arow0 = bm * 256;
  const int brow0 = bn * 256;

  // frag-read constants
  const int rA0 = wm * 128 + (lane & 15);
  const int rB0 = wn * 64 + (lane & 15);
  const int kq  = lane >> 4;                  // 0..3
  const int swA = rA0 & 7, swB = rB0 & 7;

  f32x4 acc[8][4];
#pragma unroll
  for (int i = 0; i < 8; ++i)
#pragma unroll
    for (int j = 0; j < 4; ++j) acc[i][j] = (f32x4){0.f, 0.f, 0.f, 0.f};

  // prologue: stage tile 0 -> buf 0, drain, barrier
#pragma unroll
  for (int r = 0; r < 4; ++r) STAGE2(0, r, 0);
  asm volatile("s_waitcnt vmcnt(0)" ::: "memory");
  __builtin_amdgcn_s_barrier();

  short8 a[4][2], bfr[4][2];
  const int KT = K >> 6;                      // 64

  for (int kt = 0; kt < KT; ++kt) {
    const int cur = kt & 1, nxt = cur ^ 1;
    const bool more = (kt + 1 < KT);
    const uint8_t* Ab = sA + cur * 32768;
    const uint8_t* Bb = sB + cur * 32768;

    // phase 0: quadrant (mi 0-3, ni 0-1)
    if (more) STAGE2(kt + 1, 0, nxt);
    READ_A(0)
    READ_B(0)
    MFMA_Q(0, 0);
    __builtin_amdgcn_s_barrier();

    // phase 1: quadrant (mi 0-3, ni 2-3)
    if (more) STAGE2(kt + 1, 1, nxt);
    READ_B(2)
    MFMA_Q(0, 1);
    __builtin_amdgcn_s_barrier();

    // phase 2: quadrant (mi 4-7, ni 0-1)
    if (more) STAGE2(kt + 1, 2, nxt);
    READ_A(1)
    MFMA_Q(1, 0);
    __builtin_amdgcn_s_barrier();

    // phase 3: quadrant (mi 4-7, ni 2-3); boundary drain for next tile
    if (more) STAGE2(kt + 1, 3, nxt);
    MFMA_Q(1, 1);
    __builtin_amdgcn_sched_barrier(0);        // pin reads/MFMA above boundary
    asm volatile("s_waitcnt vmcnt(0)" ::: "memory");
    __builtin_amdgcn_s_barrier();
  }

  // epilogue: m89 C/D mapping; f32 store = bf16 bits << 16
  const int c0 = bn * 256 + wn * 64 + (lane & 15);
  const int r0q = bm * 256 + wm * 128 + ((lane >> 4) << 2);
#pragma unroll
  for (int mi = 0; mi < 8; ++mi)
#pragma unroll
    for (int j = 0; j < 4; ++j) {
      const size_t row = (size_t)(r0q + mi * 16 + j);
#pragma unroll
      for (int ni = 0; ni < 4; ++ni)
        C32[row * N + c0 + ni * 16] = ((u32)bf16_rne(acc[mi][ni][j])) << 16;
    }
}

// ---------------------------------------------------------------------------
extern "C" void kernel_launch(void* const* d_in, const int* in_sizes, int n_in,
                              void* d_out, int out_size, void* d_ws, size_t ws_size,
                              hipStream_t stream) {
  const float* A = (const float*)d_in[0];    // f32 row-major [M,K]
  const float* W = (const float*)d_in[1];    // f32 row-major [N,K]
  const float* WS = (const float*)d_in[2];   // f32 [N/128,K/128]
  const int K = 4096, N = 4096;
  const int M = in_sizes[0] / K;             // 8192
  const int Mh = M / 2;                      // 4096 per GEMM pass

  // workspace: [0,32MiB) AD (half-M bf16) | [32,64MiB) WD (bf16) — 64 MiB total
  u16* ADh = (u16*)d_ws;
  u16* WDp = ADh + (size_t)Mh * K;
  u32* C = (u32*)d_out;

  dequant_w<<<N * 2, 256, 0, stream>>>(W, WS, WDp, K, K / 128);

  quant_dequant_a<<<Mh * 2, 256, 0, stream>>>(A, ADh, K);
  gemm_8p<<<(Mh / 256) * (N / 256), 512, 0, stream>>>(ADh, WDp, C, N, K);

  quant_dequant_a<<<Mh * 2, 256, 0, stream>>>(A + (size_t)Mh * K, ADh, K);
  gemm_8p<<<(Mh / 256) * (N / 256), 512, 0, stream>>>(ADh, WDp,
                                                      C + (size_t)Mh * N, N, K);
}